// Round 1
// 11368.571 us; speedup vs baseline: 1.2547x; 1.2547x over previous
//
#include <hip/hip_runtime.h>
#include <hip/hip_bf16.h>

#define E_ 768
#define E2_ 1536
#define E3_ 2304
#define U_ 256
#define NORM_ 27.712812921102035f

typedef unsigned int u32;
typedef unsigned long long u64;

// ---------------- static device workspace (~8.3 MB) ----------------
__device__ __align__(16) float g_Q[U_ * E_];       // D @ Wq + bq
__device__ __align__(16) float g_WQg[U_ * E2_];    // (Wk @ q_t)/norm, row t
__device__ __align__(16) float g_WKVT[E_ * E2_];   // (Wk@Wv)^T : [e][k]
__device__ __align__(16) float g_buf[U_ * E2_];    // attention memory
__device__ __align__(16) float g_vb[E_];           // bk@Wv + bv
__device__ __align__(16) float g_scores[U_];
__device__ __align__(16) float g_att[E_];
__device__ __align__(16) float g_so[E2_];
__device__ __align__(16) float g_gh[E2_];
__device__ __align__(16) float g_hstate[8 * E2_];
// hierarchical barrier state: 16 arrival counters on separate 128B lines + epoch
__device__ __align__(128) int g_cnt[16 * 32];
__device__ __align__(128) int g_epoch;

__device__ __forceinline__ float bflo(u32 v){ return __uint_as_float(v << 16); }
__device__ __forceinline__ float bfhi(u32 v){ return __uint_as_float(v & 0xffff0000u); }

// pack two fp32 into one u32 holding two bf16 (RNE)
__device__ __forceinline__ u32 packbf(float lo, float hi){
  u32 a = __float_as_uint(lo), b = __float_as_uint(hi);
  a = (a + 0x7FFFu + ((a >> 16) & 1u)) >> 16;
  b = (b + 0x7FFFu + ((b >> 16) & 1u)) & 0xFFFF0000u;
  return (a & 0xFFFFu) | b;
}

// ---- coherent (LLC, cross-XCD) accesses for the few exchanged arrays ----
__device__ __forceinline__ float aload(const float* p){
  return __hip_atomic_load(p, __ATOMIC_RELAXED, __HIP_MEMORY_SCOPE_AGENT);
}
__device__ __forceinline__ void astore(float* p, float v){
  __hip_atomic_store(p, v, __ATOMIC_RELAXED, __HIP_MEMORY_SCOPE_AGENT);
}
__device__ __forceinline__ float2 aload2(const float* p){
  u64 v = __hip_atomic_load((u64*)p, __ATOMIC_RELAXED, __HIP_MEMORY_SCOPE_AGENT);
  float2 r;
  r.x = __uint_as_float((u32)(v & 0xffffffffu));
  r.y = __uint_as_float((u32)(v >> 32));
  return r;
}

__device__ __forceinline__ float wsum(float v){
#pragma unroll
  for (int o = 32; o > 0; o >>= 1) v += __shfl_xor(v, o, 64);
  return v;
}
__device__ __forceinline__ float wmax(float v){
#pragma unroll
  for (int o = 32; o > 0; o >>= 1) v = fmaxf(v, __shfl_xor(v, o, 64));
  return v;
}

// ---------------- init: barrier words, hstate/gh (blocks 0..63), vb (64..75) ----------------
__global__ __launch_bounds__(256) void init_kernel(const float* h0g, const float* h0s,
                                                   const float* bk, const float* Wv,
                                                   const float* bv)
{
  __shared__ float acc4[4][64];
  int tid = threadIdx.x;
  if (blockIdx.x < 64) {
    int i = blockIdx.x * 256 + tid;
    int n = 64 * 256;
    if (i < 16 * 32) g_cnt[i] = 0;
    if (i == 0) g_epoch = 0;
    for (int j = i; j < 8 * E2_; j += n) g_hstate[j] = h0s[j % E2_];
    for (int j = i; j < E2_; j += n) g_gh[j] = h0g[j];
  } else {
    int b = blockIdx.x - 64;          // 0..11
    int o = b * 64 + (tid & 63);
    int w = tid >> 6;
    float s = 0.f;
    for (int i2 = w * 192; i2 < w * 192 + 192; ++i2)
      s = fmaf(bk[i2], Wv[(size_t)i2 * E_ + o], s);
    acc4[w][tid & 63] = s;
    __syncthreads();
    if (w == 0)
      g_vb[o] = acc4[0][tid & 63] + acc4[1][tid & 63] + acc4[2][tid & 63] + acc4[3][tid & 63] + bv[o];
  }
}

// ---------------- fp32 tiled GEMM: C = scale*(A@B) + bias ----------------
template<int ASRC, int BNK, int DST, int TC>
__global__ __launch_bounds__(256) void gemm32(const float* __restrict__ Aext, int lda,
                                              const float* __restrict__ B, int ldb,
                                              const float* __restrict__ bias, float scale,
                                              int ldc, int M, int N, int K)
{
  const float* A = (ASRC == 1) ? g_Q : Aext;
  float* C = (DST == 0) ? g_Q : (DST == 1) ? g_WQg : g_WKVT;
  __shared__ float As[64][17];
  __shared__ float Bs[16][65];
  int tid = threadIdx.x;
  int tx = tid & 15, ty = tid >> 4;
  int m0 = blockIdx.y * 64, n0 = blockIdx.x * 64;
  float acc[4][4] = {{0.f}};
  for (int k0 = 0; k0 < K; k0 += 16) {
#pragma unroll
    for (int i = 0; i < 4; ++i) {
      int li = tid + 256 * i;
      int m = li >> 4, kk = li & 15;
      As[m][kk] = A[(size_t)(m0 + m) * lda + k0 + kk];
    }
#pragma unroll
    for (int i = 0; i < 4; ++i) {
      int li = tid + 256 * i;
      if (BNK) {
        int n = li >> 4, kk = li & 15;
        Bs[kk][n] = B[(size_t)(n0 + n) * ldb + k0 + kk];
      } else {
        int kk = li >> 6, n = li & 63;
        Bs[kk][n] = B[(size_t)(k0 + kk) * ldb + n0 + n];
      }
    }
    __syncthreads();
#pragma unroll
    for (int kk = 0; kk < 16; ++kk) {
      float av[4], bv4[4];
#pragma unroll
      for (int i = 0; i < 4; ++i) av[i] = As[ty * 4 + i][kk];
#pragma unroll
      for (int j = 0; j < 4; ++j) bv4[j] = Bs[kk][tx * 4 + j];
#pragma unroll
      for (int i = 0; i < 4; ++i)
#pragma unroll
        for (int j = 0; j < 4; ++j) acc[i][j] = fmaf(av[i], bv4[j], acc[i][j]);
    }
    __syncthreads();
  }
#pragma unroll
  for (int i = 0; i < 4; ++i)
#pragma unroll
    for (int j = 0; j < 4; ++j) {
      int m = m0 + ty * 4 + i, n = n0 + tx * 4 + j;
      float c = acc[i][j] * scale;
      if (bias) c += bias[n];
      if (TC) C[(size_t)n * ldc + m] = c;
      else    C[(size_t)m * ldc + n] = c;
    }
}

// ---------------- persistent sequential kernel ----------------
struct SeqArgs {
  const float *dialogue, *sWih_f, *sWih_b, *sWhh_f, *sWhh_b,
      *sbih_f, *sbih_b, *sbhh_f, *sbhh_b,
      *gWih_f, *gWih_b, *gWhh_f, *gWhh_b, *gbih_f, *gbih_b, *gbhh_f, *gbhh_b,
      *att0;
  const int* speakers;
  float* out;   // fp32: [U*2E buf][U*2E so]
};

// Fence-free barrier. All cross-block data traffic uses agent-scope relaxed
// atomics (sc-bit, coherent-at-LLC accesses) so NO cache-wide release/acquire
// maintenance (buffer_wbl2 / buffer_inv) is needed. Ordering: the compiler
// drains vmcnt(0) at each wave's __syncthreads before the arrival RMW
// (store-ack from the coherence point == release for sc data); readers after
// the barrier fetch fresh from the coherence point by construction.
__device__ __forceinline__ void gbar(int target)
{
  __syncthreads();                          // per-wave vmcnt(0) drain here
  if (threadIdx.x == 0) {
    asm volatile("s_waitcnt vmcnt(0)" ::: "memory");
    __hip_atomic_fetch_add(&g_cnt[(blockIdx.x & 15) * 32], 1,
                           __ATOMIC_RELAXED, __HIP_MEMORY_SCOPE_AGENT);
    if (blockIdx.x == 0) {
      int need = 256 * target;
      for (;;) {
        int sum = 0;
#pragma unroll
        for (int i = 0; i < 16; ++i)
          sum += __hip_atomic_load(&g_cnt[i * 32], __ATOMIC_RELAXED, __HIP_MEMORY_SCOPE_AGENT);
        if (sum >= need) break;
      }
      __hip_atomic_store(&g_epoch, target, __ATOMIC_RELAXED, __HIP_MEMORY_SCOPE_AGENT);
    } else {
      while (__hip_atomic_load(&g_epoch, __ATOMIC_RELAXED, __HIP_MEMORY_SCOPE_AGENT) < target)
        __builtin_amdgcn_s_sleep(1);
    }
    asm volatile("" ::: "memory");
  }
  __syncthreads();
}

__global__ __launch_bounds__(256, 1) void seq_kernel(SeqArgs a)
{
  const int tid = threadIdx.x, wg = blockIdx.x;
  const int wave = tid >> 6, lane = tid & 63;
  const int h0 = wg * 3;

  __shared__ float ghs_s[18], ghg_s[18], sxu[18], gxu[18], gxs[18];
  __shared__ float red4[4], att_s[3], pnum[4][4], pmax[4];
  __shared__ float V_lds[U_][3];
  // per-phase LDS staging of coherently-read vectors (read once from LLC,
  // then reused from LDS by all waves)
  __shared__ float2 bufc[768];     // this block's immutable g_buf row wg
  __shared__ float2 rowp[768];     // scratch: g_buf row t-1
  __shared__ float2 hv_s[2][384];  // g_hstate[sp] fwd/bwd
  __shared__ float2 gv_s[2][384];  // g_gh fwd/bwd
  __shared__ float2 att_g[384];    // full attention vector
  __shared__ float2 so_g[768];     // full speaker output

  // ---- per-block weight slices: fp32 -> packed bf16 registers ----
  u32 wSA[5][6], wSU[5][6], wSHH[5][6], wGHH[5][6], wGSO[5][12], wGU[5][6];
  float bSH[5], bGH[5], bSI[5], bGI[5];
#pragma unroll
  for (int q = 0; q < 5; ++q) {
    int sr = wave + 4 * q;
    if (sr < 18) {
      int dir = sr / 9, lr = sr - dir * 9, g = lr / 3, d = lr - g * 3;
      int gr = g * E_ + h0 + d;
      const float* pa  = (dir ? a.sWih_b : a.sWih_f) + (size_t)gr * E2_;
      const float* ph  = (dir ? a.sWhh_b : a.sWhh_f) + (size_t)gr * E_;
      const float* pgs = (dir ? a.gWih_b : a.gWih_f) + (size_t)gr * E3_;
      const float* pgh = (dir ? a.gWhh_b : a.gWhh_f) + (size_t)gr * E_;
#pragma unroll
      for (int pp = 0; pp < 6; ++pp) {
        int j2 = 2 * (lane + 64 * pp);
        wSA[q][pp]  = packbf(pa[j2], pa[j2 + 1]);
        wSU[q][pp]  = packbf(pa[768 + j2], pa[768 + j2 + 1]);
        wSHH[q][pp] = packbf(ph[j2], ph[j2 + 1]);
        wGHH[q][pp] = packbf(pgh[j2], pgh[j2 + 1]);
        wGU[q][pp]  = packbf(pgs[1536 + j2], pgs[1536 + j2 + 1]);
      }
#pragma unroll
      for (int pp = 0; pp < 12; ++pp) {
        int j2 = 2 * (lane + 64 * pp);
        wGSO[q][pp] = packbf(pgs[j2], pgs[j2 + 1]);
      }
      bSH[q] = (dir ? a.sbhh_b : a.sbhh_f)[gr];
      bSI[q] = (dir ? a.sbih_b : a.sbih_f)[gr];
      bGH[q] = (dir ? a.gbhh_b : a.gbhh_f)[gr];
      bGI[q] = (dir ? a.gbih_b : a.gbih_f)[gr];
    }
  }
  // ---- wKV: 3 columns of Wk@Wv for this block (fp32) ----
  float wKV[24];
  if (wave < 3) {
    const float* kv = g_WKVT + (size_t)(h0 + wave) * E2_;
#pragma unroll
    for (int pp = 0; pp < 12; ++pp) {
      int j2 = 2 * (lane + 64 * pp);
      wKV[2 * pp] = kv[j2]; wKV[2 * pp + 1] = kv[j2 + 1];
    }
  }
  const float vb0 = g_vb[h0], vb1 = g_vb[h0 + 1], vb2 = g_vb[h0 + 2];

  int bt = 0;
  for (int t = 0; t < U_; ++t) {
    const int sp = a.speakers[t] & 7;
    const float2* uv = (const float2*)(a.dialogue + (size_t)t * E_);   // 384 float2

    // ---------- P0: stage coherent vectors, scores, recurrent matvecs, V[t-1] ----------
    if (t > 0) {
      // g_buf row t-1 (fresh from last step's P3). Block t-1 keeps it
      // permanently as its score operand; everyone needs it for the V slice.
      float2* dst = (wg == t - 1) ? bufc : rowp;
      const float* src = g_buf + (size_t)(t - 1) * E2_;
      for (int i = tid; i < 768; i += 256) dst[i] = aload2(src + 2 * i);
    }
    {
      const float* hs = g_hstate + (size_t)(sp * 2) * E_;
      for (int i = tid; i < 384; i += 256) {
        hv_s[0][i] = aload2(hs + 2 * i);
        hv_s[1][i] = aload2(hs + E_ + 2 * i);
        gv_s[0][i] = aload2(g_gh + 2 * i);
        gv_s[1][i] = aload2(g_gh + E_ + 2 * i);
      }
    }
    __syncthreads();

    if (wg < t) {
      const float2* wq = (const float2*)(g_WQg + (size_t)t * E2_);  // static, cached
      float s = 0.f;
#pragma unroll
      for (int pp = 0; pp < 3; ++pp) {
        int j = tid + 256 * pp;
        float2 x = bufc[j];
        float2 w = wq[j];
        s = fmaf(x.x, w.x, s);
        s = fmaf(x.y, w.y, s);
      }
      s = wsum(s);
      if (lane == 0) red4[wave] = s;
      __syncthreads();
      if (tid == 0) astore(&g_scores[wg], red4[0] + red4[1] + red4[2] + red4[3]);
    } else if (wg == t) {
      if (tid == 0) astore(&g_scores[wg], 0.f);  // buf row t zero; const shift dropped (softmax-inv)
    }
#pragma unroll
    for (int q = 0; q < 5; ++q) {
      int sr = wave + 4 * q;
      if (sr < 18) {
        int dir = sr / 9;
        float s1 = 0.f, s2 = 0.f, s3 = 0.f, s4 = 0.f;
#pragma unroll
        for (int pp = 0; pp < 6; ++pp) {
          int j = lane + 64 * pp;
          u32 v1 = wSHH[q][pp], v2 = wGHH[q][pp], v3 = wSU[q][pp], v4 = wGU[q][pp];
          float2 xh = hv_s[dir][j];
          float2 xg = gv_s[dir][j];
          float2 xu = uv[j];
          s1 = fmaf(bflo(v1), xh.x, s1); s1 = fmaf(bfhi(v1), xh.y, s1);
          s2 = fmaf(bflo(v2), xg.x, s2); s2 = fmaf(bfhi(v2), xg.y, s2);
          s3 = fmaf(bflo(v3), xu.x, s3); s3 = fmaf(bfhi(v3), xu.y, s3);
          s4 = fmaf(bflo(v4), xu.x, s4); s4 = fmaf(bfhi(v4), xu.y, s4);
        }
        s1 = wsum(s1); s2 = wsum(s2); s3 = wsum(s3); s4 = wsum(s4);
        if (lane == 0) {
          ghs_s[sr] = s1 + bSH[q]; ghg_s[sr] = s2 + bGH[q];
          sxu[sr] = s3 + bSI[q];   gxu[sr] = s4 + bGI[q];
        }
      }
    }
    if (t > 0 && wave < 3) {
      const float2* br = (wg == t - 1) ? bufc : rowp;   // LDS-staged row t-1
      float s = 0.f;
#pragma unroll
      for (int pp = 0; pp < 12; ++pp) {
        int j = lane + 64 * pp;
        float2 x = br[j];
        s = fmaf(wKV[2 * pp], x.x, s);
        s = fmaf(wKV[2 * pp + 1], x.y, s);
      }
      s = wsum(s);
      if (lane == 0) V_lds[t - 1][wave] = s + (wave == 0 ? vb0 : (wave == 1 ? vb1 : vb2));
    }
    gbar(++bt);

    // ---------- P1: max-subtracted softmax + att (3 dims per block) ----------
    if (t == 0) {
      if (tid < 3) { float v = a.att0[h0 + tid]; att_s[tid] = v; astore(&g_att[h0 + tid], v); }
    } else {
      float sc = (tid <= t) ? aload(&g_scores[tid]) : -3.0e38f;
      float m = wmax(sc);
      if (lane == 0) pmax[wave] = m;
      __syncthreads();
      float mall = fmaxf(fmaxf(pmax[0], pmax[1]), fmaxf(pmax[2], pmax[3]));
      float e = 0.f, n0 = 0.f, n1 = 0.f, n2 = 0.f;
      if (tid <= t) {
        e = expf(sc - mall);
        if (tid < t) { n0 = e * V_lds[tid][0]; n1 = e * V_lds[tid][1]; n2 = e * V_lds[tid][2]; }
        else         { n0 = e * vb0; n1 = e * vb1; n2 = e * vb2; }
      }
      e = wsum(e); n0 = wsum(n0); n1 = wsum(n1); n2 = wsum(n2);
      if (lane == 0) { pnum[wave][0] = e; pnum[wave][1] = n0; pnum[wave][2] = n1; pnum[wave][3] = n2; }
      __syncthreads();
      if (tid < 3) {
        float den = pnum[0][0] + pnum[1][0] + pnum[2][0] + pnum[3][0];
        float nn = pnum[0][tid + 1] + pnum[1][tid + 1] + pnum[2][tid + 1] + pnum[3][tid + 1];
        float v = nn / den;
        att_s[tid] = v; astore(&g_att[h0 + tid], v);
      }
    }
    gbar(++bt);

    // ---------- P2: speaker GRU ----------
    for (int i = tid; i < 384; i += 256) att_g[i] = aload2(g_att + 2 * i);
    __syncthreads();
#pragma unroll
    for (int q = 0; q < 5; ++q) {
      int sr = wave + 4 * q;
      if (sr < 18) {
        float s = 0.f;
#pragma unroll
        for (int pp = 0; pp < 6; ++pp) {
          int j = lane + 64 * pp;
          u32 v = wSA[q][pp];
          float2 x = att_g[j];
          s = fmaf(bflo(v), x.x, s); s = fmaf(bfhi(v), x.y, s);
        }
        s = wsum(s);
        if (lane == 0) gxs[sr] = s;
      }
    }
    __syncthreads();
    if (tid < 6) {
      int dir = tid / 3, d = tid - dir * 3, h = h0 + d;
      float xr = gxs[dir * 9 + d]     + sxu[dir * 9 + d];
      float xz = gxs[dir * 9 + 3 + d] + sxu[dir * 9 + 3 + d];
      float xn = gxs[dir * 9 + 6 + d] + sxu[dir * 9 + 6 + d];
      float hr = ghs_s[dir * 9 + d], hz = ghs_s[dir * 9 + 3 + d], hn = ghs_s[dir * 9 + 6 + d];
      float hp = ((const float*)hv_s[dir])[h];
      float r = 1.f / (1.f + expf(-(xr + hr)));
      float z = 1.f / (1.f + expf(-(xz + hz)));
      float n = tanhf(xn + r * hn);
      float hnew = (1.f - z) * n + z * hp;
      astore(&g_hstate[(size_t)(sp * 2 + dir) * E_ + h], hnew);
      float resid = dir ? a.dialogue[(size_t)t * E_ + h] : att_s[d];
      float so = hnew + resid;
      astore(&g_so[dir * E_ + h], so);
      a.out[(size_t)U_ * E2_ + (size_t)t * E2_ + dir * E_ + h] = so;
    }
    gbar(++bt);

    // ---------- P3: global GRU ----------
    for (int i = tid; i < 768; i += 256) so_g[i] = aload2(g_so + 2 * i);
    __syncthreads();
#pragma unroll
    for (int q = 0; q < 5; ++q) {
      int sr = wave + 4 * q;
      if (sr < 18) {
        float s = 0.f;
#pragma unroll
        for (int pp = 0; pp < 12; ++pp) {
          int j = lane + 64 * pp;
          u32 v = wGSO[q][pp];
          float2 x = so_g[j];
          s = fmaf(bflo(v), x.x, s); s = fmaf(bfhi(v), x.y, s);
        }
        s = wsum(s);
        if (lane == 0) gxs[sr] = s;
      }
    }
    __syncthreads();
    if (tid < 6) {
      int dir = tid / 3, d = tid - dir * 3, h = h0 + d;
      float xr = gxs[dir * 9 + d]     + gxu[dir * 9 + d];
      float xz = gxs[dir * 9 + 3 + d] + gxu[dir * 9 + 3 + d];
      float xn = gxs[dir * 9 + 6 + d] + gxu[dir * 9 + 6 + d];
      float hr = ghg_s[dir * 9 + d], hz = ghg_s[dir * 9 + 3 + d], hn = ghg_s[dir * 9 + 6 + d];
      float hp = ((const float*)gv_s[dir])[h];
      float r = 1.f / (1.f + expf(-(xr + hr)));
      float z = 1.f / (1.f + expf(-(xz + hz)));
      float n = tanhf(xn + r * hn);
      float hnew = (1.f - z) * n + z * hp;
      astore(&g_gh[dir * E_ + h], hnew);
      astore(&g_buf[(size_t)t * E2_ + dir * E_ + h], hnew);
      a.out[(size_t)t * E2_ + dir * E_ + h] = hnew;
    }
    gbar(++bt);
  }
}

// ---------------- host ----------------
extern "C" void kernel_launch(void* const* d_in, const int* in_sizes, int n_in,
                              void* d_out, int out_size, void* d_ws, size_t ws_size,
                              hipStream_t stream)
{
  (void)in_sizes; (void)n_in; (void)out_size; (void)d_ws; (void)ws_size;
  const float* dialogue = (const float*)d_in[0];
  const int* speakers = (const int*)d_in[1];
  const float* Wq = (const float*)d_in[2];
  const float* bq = (const float*)d_in[3];
  const float* Wk = (const float*)d_in[4];
  const float* bk = (const float*)d_in[5];
  const float* Wv = (const float*)d_in[6];
  const float* bv = (const float*)d_in[7];
  const float* sWih_f = (const float*)d_in[8];
  const float* sWhh_f = (const float*)d_in[9];
  const float* sbih_f = (const float*)d_in[10];
  const float* sbhh_f = (const float*)d_in[11];
  const float* sWih_b = (const float*)d_in[12];
  const float* sWhh_b = (const float*)d_in[13];
  const float* sbih_b = (const float*)d_in[14];
  const float* sbhh_b = (const float*)d_in[15];
  const float* gWih_f = (const float*)d_in[16];
  const float* gWhh_f = (const float*)d_in[17];
  const float* gbih_f = (const float*)d_in[18];
  const float* gbhh_f = (const float*)d_in[19];
  const float* gWih_b = (const float*)d_in[20];
  const float* gWhh_b = (const float*)d_in[21];
  const float* gbih_b = (const float*)d_in[22];
  const float* gbhh_b = (const float*)d_in[23];
  const float* h0_global = (const float*)d_in[24];
  const float* h0_speaker = (const float*)d_in[25];
  const float* att0 = (const float*)d_in[26];

  init_kernel<<<dim3(76), dim3(256), 0, stream>>>(h0_global, h0_speaker, bk, Wv, bv);

  // g_Q = D @ Wq + bq
  gemm32<0, 0, 0, 0><<<dim3(12, 4), dim3(256), 0, stream>>>(
      dialogue, 768, Wq, 768, bq, 1.f, 768, 256, 768, 768);
  // g_WQg = g_Q @ Wk^T / norm
  gemm32<1, 1, 1, 0><<<dim3(24, 4), dim3(256), 0, stream>>>(
      nullptr, 768, Wk, 768, nullptr, 1.f / NORM_, 1536, 256, 1536, 768);
  // g_WKVT[e][k] = (Wk @ Wv)[k][e]
  gemm32<0, 0, 2, 1><<<dim3(12, 24), dim3(256), 0, stream>>>(
      Wk, 768, Wv, 768, nullptr, 1.f, 1536, 1536, 768, 768);

  SeqArgs args;
  args.dialogue = dialogue;
  args.sWih_f = sWih_f; args.sWih_b = sWih_b; args.sWhh_f = sWhh_f; args.sWhh_b = sWhh_b;
  args.sbih_f = sbih_f; args.sbih_b = sbih_b; args.sbhh_f = sbhh_f; args.sbhh_b = sbhh_b;
  args.gWih_f = gWih_f; args.gWih_b = gWih_b; args.gWhh_f = gWhh_f; args.gWhh_b = gWhh_b;
  args.gbih_f = gbih_f; args.gbih_b = gbih_b; args.gbhh_f = gbhh_f; args.gbhh_b = gbhh_b;
  args.att0 = att0; args.speakers = speakers;
  args.out = (float*)d_out;

  seq_kernel<<<dim3(256), dim3(256), 0, stream>>>(args);
}

// Round 2
// 7125.089 us; speedup vs baseline: 2.0020x; 1.5956x over previous
//
#include <hip/hip_runtime.h>
#include <hip/hip_bf16.h>

#define E_ 768
#define E2_ 1536
#define E3_ 2304
#define U_ 256
#define NORM_ 27.712812921102035f

typedef unsigned int u32;
typedef unsigned long long u64;

// ---------------- static device workspace ----------------
__device__ __align__(16) float g_Q[U_ * E_];       // D @ Wq + bq
__device__ __align__(16) float g_WQg[U_ * E2_];    // (Wk @ q_t)/norm, row t
__device__ __align__(16) float g_WKVT[E_ * E2_];   // (Wk@Wv)^T : [e][k]
__device__ __align__(16) float g_vb[E_];           // bk@Wv + bv
__device__ int g_run;                              // run counter (tag base)

// mailboxes: u64 = {tag:32 (hi) | fp32 payload (lo)}
__device__ __align__(64) u64 g_mb_bg[U_ * 8];      // buf row t == gh^t, 6 used/block
__device__ __align__(64) u64 g_mb_so[U_ * 8];      // speaker output, 6 used/block
__device__ __align__(64) u64 g_mb_sc[2 * U_];      // scores, parity-slotted by target step
__device__ __align__(64) u64 g_mb_v [U_ * 4];      // v row dims, 3 used/block
__device__ __align__(64) u64 g_mb_h [U_ * 8 * 8];  // hstate per (block, speaker), 6 used

__device__ __forceinline__ float bflo(u32 v){ return __uint_as_float(v << 16); }
__device__ __forceinline__ float bfhi(u32 v){ return __uint_as_float(v & 0xffff0000u); }

__device__ __forceinline__ u32 packbf(float lo, float hi){
  u32 a = __float_as_uint(lo), b = __float_as_uint(hi);
  a = (a + 0x7FFFu + ((a >> 16) & 1u)) >> 16;
  b = (b + 0x7FFFu + ((b >> 16) & 1u)) & 0xFFFF0000u;
  return (a & 0xFFFFu) | b;
}

// coherent (LLC) accesses for mailboxes
__device__ __forceinline__ u64 aload64(const u64* p){
  return __hip_atomic_load(p, __ATOMIC_RELAXED, __HIP_MEMORY_SCOPE_AGENT);
}
__device__ __forceinline__ void astore64(u64* p, u64 v){
  __hip_atomic_store(p, v, __ATOMIC_RELAXED, __HIP_MEMORY_SCOPE_AGENT);
}
__device__ __forceinline__ u64 pk(float f, u32 tag){ return (u64)__float_as_uint(f) | ((u64)tag << 32); }
__device__ __forceinline__ float pf(u64 v){ return __uint_as_float((u32)v); }
__device__ __forceinline__ u32 ptag(u64 v){ return (u32)(v >> 32); }

__device__ __forceinline__ float wsum(float v){
#pragma unroll
  for (int o = 32; o > 0; o >>= 1) v += __shfl_xor(v, o, 64);
  return v;
}
__device__ __forceinline__ float wmax(float v){
#pragma unroll
  for (int o = 32; o > 0; o >>= 1) v = fmaxf(v, __shfl_xor(v, o, 64));
  return v;
}

// ---------------- init: run counter + vb ----------------
__global__ __launch_bounds__(256) void init_kernel(const float* bk, const float* Wv,
                                                   const float* bv)
{
  __shared__ float acc4[4][64];
  int tid = threadIdx.x;
  if (blockIdx.x == 0 && tid == 0) g_run = g_run + 1;
  int b = blockIdx.x;               // 0..11
  int o = b * 64 + (tid & 63);
  int w = tid >> 6;
  float s = 0.f;
  for (int i2 = w * 192; i2 < w * 192 + 192; ++i2)
    s = fmaf(bk[i2], Wv[(size_t)i2 * E_ + o], s);
  acc4[w][tid & 63] = s;
  __syncthreads();
  if (w == 0)
    g_vb[o] = acc4[0][tid & 63] + acc4[1][tid & 63] + acc4[2][tid & 63] + acc4[3][tid & 63] + bv[o];
}

// ---------------- fp32 tiled GEMM: C = scale*(A@B) + bias ----------------
template<int ASRC, int BNK, int DST, int TC>
__global__ __launch_bounds__(256) void gemm32(const float* __restrict__ Aext, int lda,
                                              const float* __restrict__ B, int ldb,
                                              const float* __restrict__ bias, float scale,
                                              int ldc, int M, int N, int K)
{
  const float* A = (ASRC == 1) ? g_Q : Aext;
  float* C = (DST == 0) ? g_Q : (DST == 1) ? g_WQg : g_WKVT;
  __shared__ float As[64][17];
  __shared__ float Bs[16][65];
  int tid = threadIdx.x;
  int tx = tid & 15, ty = tid >> 4;
  int m0 = blockIdx.y * 64, n0 = blockIdx.x * 64;
  float acc[4][4] = {{0.f}};
  for (int k0 = 0; k0 < K; k0 += 16) {
#pragma unroll
    for (int i = 0; i < 4; ++i) {
      int li = tid + 256 * i;
      int m = li >> 4, kk = li & 15;
      As[m][kk] = A[(size_t)(m0 + m) * lda + k0 + kk];
    }
#pragma unroll
    for (int i = 0; i < 4; ++i) {
      int li = tid + 256 * i;
      if (BNK) {
        int n = li >> 4, kk = li & 15;
        Bs[kk][n] = B[(size_t)(n0 + n) * ldb + k0 + kk];
      } else {
        int kk = li >> 6, n = li & 63;
        Bs[kk][n] = B[(size_t)(k0 + kk) * ldb + n0 + n];
      }
    }
    __syncthreads();
#pragma unroll
    for (int kk = 0; kk < 16; ++kk) {
      float av[4], bv4[4];
#pragma unroll
      for (int i = 0; i < 4; ++i) av[i] = As[ty * 4 + i][kk];
#pragma unroll
      for (int j = 0; j < 4; ++j) bv4[j] = Bs[kk][tx * 4 + j];
#pragma unroll
      for (int i = 0; i < 4; ++i)
#pragma unroll
        for (int j = 0; j < 4; ++j) acc[i][j] = fmaf(av[i], bv4[j], acc[i][j]);
    }
    __syncthreads();
  }
#pragma unroll
  for (int i = 0; i < 4; ++i)
#pragma unroll
    for (int j = 0; j < 4; ++j) {
      int m = m0 + ty * 4 + i, n = n0 + tx * 4 + j;
      float c = acc[i][j] * scale;
      if (bias) c += bias[n];
      if (TC) C[(size_t)n * ldc + m] = c;
      else    C[(size_t)m * ldc + n] = c;
    }
}

// ---------------- persistent sequential kernel ----------------
struct SeqArgs {
  const float *dialogue, *sWih_f, *sWih_b, *sWhh_f, *sWhh_b,
      *sbih_f, *sbih_b, *sbhh_f, *sbhh_b,
      *gWih_f, *gWih_b, *gWhh_f, *gWhh_b, *gbih_f, *gbih_b, *gbhh_f, *gbhh_b,
      *att0, *h0g, *h0s;
  const int* speakers;
  float* out;   // fp32: [U*2E buf][U*2E so]
};

__global__ __launch_bounds__(256, 1) void seq_kernel(SeqArgs a)
{
  const int tid = threadIdx.x, wg = blockIdx.x;
  const int wave = tid >> 6, lane = tid & 63;
  const int h0 = wg * 3;

  __shared__ float ghs_s[18], ghg_s[18], sxu[18], gxu[18], gxs[18];
  __shared__ float red4[4], red4b[4], att_s[3], pnum[4][4], pmax[4];
  __shared__ float den_s;
  __shared__ float Mvb_l[18], A0_l[18];
  __shared__ float V_lds[U_][3];
  __shared__ float M_l[18][U_];       // M[row][j] = wSA_row . v_j
  __shared__ float ghrow[E2_];        // buf row t-1 == gh^{t-1}
  __shared__ float bufc[E2_];         // this block's own buf row (row wg)
  __shared__ float hv[E2_];           // hstate[sp] fwd/bwd
  __shared__ float so_f[E2_];         // gathered speaker output
  __shared__ float vfull[E_];         // gathered v row t-1
  __shared__ float e_lds[U_];
  __shared__ int spk_l[U_], locc_l[U_];

  // ---- per-block weight slices: fp32 -> packed bf16 registers ----
  u32 wSA[5][6], wSU[5][6], wSHH[5][6], wGHH[5][6], wGSO[5][12], wGU[5][6];
  float bSH[5], bGH[5], bSI[5], bGI[5];
#pragma unroll
  for (int q = 0; q < 5; ++q) {
    int sr = wave + 4 * q;
    if (sr < 18) {
      int dir = sr / 9, lr = sr - dir * 9, g = lr / 3, d = lr - g * 3;
      int gr = g * E_ + h0 + d;
      const float* pa  = (dir ? a.sWih_b : a.sWih_f) + (size_t)gr * E2_;
      const float* ph  = (dir ? a.sWhh_b : a.sWhh_f) + (size_t)gr * E_;
      const float* pgs = (dir ? a.gWih_b : a.gWih_f) + (size_t)gr * E3_;
      const float* pgh = (dir ? a.gWhh_b : a.gWhh_f) + (size_t)gr * E_;
#pragma unroll
      for (int pp = 0; pp < 6; ++pp) {
        int j2 = 2 * (lane + 64 * pp);
        wSA[q][pp]  = packbf(pa[j2], pa[j2 + 1]);
        wSU[q][pp]  = packbf(pa[768 + j2], pa[768 + j2 + 1]);
        wSHH[q][pp] = packbf(ph[j2], ph[j2 + 1]);
        wGHH[q][pp] = packbf(pgh[j2], pgh[j2 + 1]);
        wGU[q][pp]  = packbf(pgs[1536 + j2], pgs[1536 + j2 + 1]);
      }
#pragma unroll
      for (int pp = 0; pp < 12; ++pp) {
        int j2 = 2 * (lane + 64 * pp);
        wGSO[q][pp] = packbf(pgs[j2], pgs[j2 + 1]);
      }
      bSH[q] = (dir ? a.sbhh_b : a.sbhh_f)[gr];
      bSI[q] = (dir ? a.sbih_b : a.sbih_f)[gr];
      bGH[q] = (dir ? a.gbhh_b : a.gbhh_f)[gr];
      bGI[q] = (dir ? a.gbih_b : a.gbih_f)[gr];
    }
  }
  // ---- wKV: 3 columns of Wk@Wv for this block (fp32) ----
  float wKV[24];
  if (wave < 3) {
    const float* kv = g_WKVT + (size_t)(h0 + wave) * E2_;
#pragma unroll
    for (int pp = 0; pp < 12; ++pp) {
      int j2 = 2 * (lane + 64 * pp);
      wKV[2 * pp] = kv[j2]; wKV[2 * pp + 1] = kv[j2 + 1];
    }
  }
  const float vb0 = g_vb[h0], vb1 = g_vb[h0 + 1], vb2 = g_vb[h0 + 2];

  // ---- speakers + last-occurrence schedule ----
  spk_l[tid] = a.speakers[tid] & 7;
  __syncthreads();
  {
    int mysp = spk_l[tid], lo = -1;
    for (int s2 = tid - 1; s2 >= 0; --s2)
      if (spk_l[s2] == mysp) { lo = s2; break; }
    locc_l[tid] = lo;
  }
  // ---- Mvb = wSA_row . vb ; A0 = wSA_row . att0 ----
#pragma unroll
  for (int q = 0; q < 5; ++q) {
    int sr = wave + 4 * q;
    if (sr < 18) {
      float s0 = 0.f, s1 = 0.f;
#pragma unroll
      for (int pp = 0; pp < 6; ++pp) {
        int j2 = 2 * (lane + 64 * pp);
        u32 w = wSA[q][pp];
        s0 = fmaf(bflo(w), g_vb[j2], s0);  s0 = fmaf(bfhi(w), g_vb[j2 + 1], s0);
        s1 = fmaf(bflo(w), a.att0[j2], s1); s1 = fmaf(bfhi(w), a.att0[j2 + 1], s1);
      }
      s0 = wsum(s0); s1 = wsum(s1);
      if (lane == 0) { Mvb_l[sr] = s0; A0_l[sr] = s1; }
    }
  }
  __syncthreads();

  const u32 rb = ((u32)g_run) << 9;   // unique tag base per run

  for (int t = 0; t < U_; ++t) {
    const int sp = spk_l[t];
    const int locc = locc_l[t];
    const u32 tagT = rb + (u32)t;
    const float2* uv = (const float2*)(a.dialogue + (size_t)t * E_);

    // ============ P0: gather bufgh^{t-1} + hstate, scores, v, matvecs ============
    if (t == 0) {
      for (int i = tid; i < E2_; i += 256) ghrow[i] = a.h0g[i];
    } else {
      const u64* p = &g_mb_bg[(size_t)tid * 8];
      u64 x0 = aload64(p),     x1 = aload64(p + 1), x2 = aload64(p + 2);
      u64 x3 = aload64(p + 3), x4 = aload64(p + 4), x5 = aload64(p + 5);
      const u32 exp = rb + (u32)(t - 1);
      for (;;) {
        bool ok = (ptag(x0) == exp) & (ptag(x1) == exp) & (ptag(x2) == exp) &
                  (ptag(x3) == exp) & (ptag(x4) == exp) & (ptag(x5) == exp);
        if (ok) break;
        if (ptag(x0) != exp) x0 = aload64(p);
        if (ptag(x1) != exp) x1 = aload64(p + 1);
        if (ptag(x2) != exp) x2 = aload64(p + 2);
        if (ptag(x3) != exp) x3 = aload64(p + 3);
        if (ptag(x4) != exp) x4 = aload64(p + 4);
        if (ptag(x5) != exp) x5 = aload64(p + 5);
      }
      ghrow[3 * tid]          = pf(x0);
      ghrow[3 * tid + 1]      = pf(x1);
      ghrow[3 * tid + 2]      = pf(x2);
      ghrow[E_ + 3 * tid]     = pf(x3);
      ghrow[E_ + 3 * tid + 1] = pf(x4);
      ghrow[E_ + 3 * tid + 2] = pf(x5);
    }
    if (locc >= 0) {
      const u64* p = &g_mb_h[((size_t)tid * 8 + sp) * 8];
      u64 x0 = aload64(p),     x1 = aload64(p + 1), x2 = aload64(p + 2);
      u64 x3 = aload64(p + 3), x4 = aload64(p + 4), x5 = aload64(p + 5);
      const u32 exp = rb + (u32)locc;
      for (;;) {
        bool ok = (ptag(x0) == exp) & (ptag(x1) == exp) & (ptag(x2) == exp) &
                  (ptag(x3) == exp) & (ptag(x4) == exp) & (ptag(x5) == exp);
        if (ok) break;
        if (ptag(x0) != exp) x0 = aload64(p);
        if (ptag(x1) != exp) x1 = aload64(p + 1);
        if (ptag(x2) != exp) x2 = aload64(p + 2);
        if (ptag(x3) != exp) x3 = aload64(p + 3);
        if (ptag(x4) != exp) x4 = aload64(p + 4);
        if (ptag(x5) != exp) x5 = aload64(p + 5);
      }
      hv[3 * tid]          = pf(x0);
      hv[3 * tid + 1]      = pf(x1);
      hv[3 * tid + 2]      = pf(x2);
      hv[E_ + 3 * tid]     = pf(x3);
      hv[E_ + 3 * tid + 1] = pf(x4);
      hv[E_ + 3 * tid + 2] = pf(x5);
    } else {
#pragma unroll
      for (int k = 0; k < 6; ++k) {
        int idx = (k / 3) * E_ + 3 * tid + (k % 3);
        hv[idx] = a.h0s[idx];
      }
    }
    __syncthreads();

    // ---- scores: critical target t (block t-1) + publish-ahead target t+1 ----
    if (t >= 1 && wg <= t - 1) {
      const bool crit = (wg == t - 1);
      const bool ahead = (t + 1 < U_);
      const float2* src = (const float2*)(crit ? ghrow : bufc);
      const float2* wq1 = (const float2*)(g_WQg + (size_t)t * E2_);
      const float2* wq2 = (const float2*)(g_WQg + (size_t)(ahead ? t + 1 : t) * E2_);
      float sa = 0.f, sb = 0.f;
#pragma unroll
      for (int pp = 0; pp < 3; ++pp) {
        int j = tid + 256 * pp;
        float2 x = src[j];
        if (crit)  { float2 w = wq1[j]; sa = fmaf(x.x, w.x, sa); sa = fmaf(x.y, w.y, sa); }
        if (ahead) { float2 w = wq2[j]; sb = fmaf(x.x, w.x, sb); sb = fmaf(x.y, w.y, sb); }
      }
      sa = wsum(sa); sb = wsum(sb);
      if (lane == 0) { red4[wave] = sa; red4b[wave] = sb; }
      __syncthreads();
      if (tid == 0) {
        if (crit)
          astore64(&g_mb_sc[(size_t)(t & 1) * U_ + wg],
                   pk(red4[0] + red4[1] + red4[2] + red4[3], tagT));
        if (ahead)
          astore64(&g_mb_sc[(size_t)((t + 1) & 1) * U_ + wg],
                   pk(red4b[0] + red4b[1] + red4b[2] + red4b[3], rb + (u32)(t + 1)));
      }
    }
    // ---- v row t-1 dims (publish) + V_lds ----
    if (t >= 1 && wave < 3) {
      const float2* gr2 = (const float2*)ghrow;
      float s = 0.f;
#pragma unroll
      for (int pp = 0; pp < 12; ++pp) {
        int j = lane + 64 * pp;
        float2 x = gr2[j];
        s = fmaf(wKV[2 * pp], x.x, s);
        s = fmaf(wKV[2 * pp + 1], x.y, s);
      }
      s = wsum(s);
      if (lane == 0) {
        float vv = s + (wave == 0 ? vb0 : (wave == 1 ? vb1 : vb2));
        V_lds[t - 1][wave] = vv;
        astore64(&g_mb_v[(size_t)wg * 4 + wave], pk(vv, tagT));
      }
    }
    // ---- recurrent + u matvecs ----
#pragma unroll
    for (int q = 0; q < 5; ++q) {
      int sr = wave + 4 * q;
      if (sr < 18) {
        int dir = sr / 9;
        const float2* hv2 = (const float2*)hv + dir * 384;
        const float2* gv2 = (const float2*)ghrow + dir * 384;
        float s1 = 0.f, s2 = 0.f, s3 = 0.f, s4 = 0.f;
#pragma unroll
        for (int pp = 0; pp < 6; ++pp) {
          int j = lane + 64 * pp;
          u32 v1 = wSHH[q][pp], v2 = wGHH[q][pp], v3 = wSU[q][pp], v4 = wGU[q][pp];
          float2 xh = hv2[j];
          float2 xg = gv2[j];
          float2 xu = uv[j];
          s1 = fmaf(bflo(v1), xh.x, s1); s1 = fmaf(bfhi(v1), xh.y, s1);
          s2 = fmaf(bflo(v2), xg.x, s2); s2 = fmaf(bfhi(v2), xg.y, s2);
          s3 = fmaf(bflo(v3), xu.x, s3); s3 = fmaf(bfhi(v3), xu.y, s3);
          s4 = fmaf(bflo(v4), xu.x, s4); s4 = fmaf(bfhi(v4), xu.y, s4);
        }
        s1 = wsum(s1); s2 = wsum(s2); s3 = wsum(s3); s4 = wsum(s4);
        if (lane == 0) {
          ghs_s[sr] = s1 + bSH[q]; ghg_s[sr] = s2 + bGH[q];
          sxu[sr] = s3 + bSI[q];   gxu[sr] = s4 + bGI[q];
        }
      }
    }
    // ---- keep own buf row ----
    if (t >= 1 && wg == t - 1)
      for (int i = tid; i < E2_; i += 256) bufc[i] = ghrow[i];
    __syncthreads();

    // ============ P1+P2: softmax (local), M-dot, speaker GRU ============
    if (t == 0) {
      if (tid < 18) gxs[tid] = A0_l[tid];
      if (tid < 3) att_s[tid] = a.att0[h0 + tid];
      __syncthreads();
    } else {
      float sc;
      if (tid < t) {
        const u64* p = &g_mb_sc[(size_t)(t & 1) * U_ + tid];
        u64 x = aload64(p);
        while (ptag(x) != tagT) x = aload64(p);
        sc = pf(x);
      } else sc = (tid == t) ? 0.f : -3.0e38f;
      float m = wmax(sc);
      if (lane == 0) pmax[wave] = m;
      __syncthreads();
      float mall = fmaxf(fmaxf(pmax[0], pmax[1]), fmaxf(pmax[2], pmax[3]));
      float e = 0.f, n0 = 0.f, n1 = 0.f, n2 = 0.f;
      if (tid <= t) {
        e = expf(sc - mall);
        if (tid < t) { n0 = e * V_lds[tid][0]; n1 = e * V_lds[tid][1]; n2 = e * V_lds[tid][2]; }
        else         { n0 = e * vb0; n1 = e * vb1; n2 = e * vb2; }
      }
      e_lds[tid] = e;
      float es = wsum(e); n0 = wsum(n0); n1 = wsum(n1); n2 = wsum(n2);
      if (lane == 0) { pnum[wave][0] = es; pnum[wave][1] = n0; pnum[wave][2] = n1; pnum[wave][3] = n2; }
      // gather v row t-1 (hop hidden behind the score hop)
      {
        const u64* p = &g_mb_v[(size_t)tid * 4];
        u64 x0 = aload64(p), x1 = aload64(p + 1), x2 = aload64(p + 2);
        for (;;) {
          bool ok = (ptag(x0) == tagT) & (ptag(x1) == tagT) & (ptag(x2) == tagT);
          if (ok) break;
          if (ptag(x0) != tagT) x0 = aload64(p);
          if (ptag(x1) != tagT) x1 = aload64(p + 1);
          if (ptag(x2) != tagT) x2 = aload64(p + 2);
        }
        vfull[3 * tid]     = pf(x0);
        vfull[3 * tid + 1] = pf(x1);
        vfull[3 * tid + 2] = pf(x2);
      }
      __syncthreads();
      if (tid == 0) den_s = pnum[0][0] + pnum[1][0] + pnum[2][0] + pnum[3][0];
      if (tid < 3) {
        float den = pnum[0][0] + pnum[1][0] + pnum[2][0] + pnum[3][0];
        float nn = pnum[0][tid + 1] + pnum[1][tid + 1] + pnum[2][tid + 1] + pnum[3][tid + 1];
        att_s[tid] = nn / den;
      }
      __syncthreads();
      // gxs_att[sr] = (sum_{j<=t-2} e_j M[sr][j] + e_{t-1}(wSA.v_{t-1}) + e_t Mvb) / den
      const float2* vf2 = (const float2*)vfull;
#pragma unroll
      for (int q = 0; q < 5; ++q) {
        int sr = wave + 4 * q;
        if (sr < 18) {
          float mc = 0.f;
#pragma unroll
          for (int pp = 0; pp < 6; ++pp) {
            int j = lane + 64 * pp;
            u32 v = wSA[q][pp];
            float2 x = vf2[j];
            mc = fmaf(bflo(v), x.x, mc); mc = fmaf(bfhi(v), x.y, mc);
          }
          mc = wsum(mc);
          float dm = 0.f;
#pragma unroll
          for (int pp = 0; pp < 4; ++pp) {
            int j = lane + 64 * pp;
            float ej = e_lds[j];
            float mj = M_l[sr][j];
            dm += (j <= t - 2) ? ej * mj : 0.f;
          }
          dm = wsum(dm);
          if (lane == 0) {
            float tot = dm + e_lds[t - 1] * mc + e_lds[t] * Mvb_l[sr];
            gxs[sr] = tot / den_s;
            M_l[sr][t - 1] = mc;
          }
        }
      }
      __syncthreads();
    }
    // ---- speaker GRU + publish h/so ----
    if (tid < 6) {
      int dir = tid / 3, d = tid - dir * 3, h = h0 + d;
      float xr = gxs[dir * 9 + d]     + sxu[dir * 9 + d];
      float xz = gxs[dir * 9 + 3 + d] + sxu[dir * 9 + 3 + d];
      float xn = gxs[dir * 9 + 6 + d] + sxu[dir * 9 + 6 + d];
      float hr = ghs_s[dir * 9 + d], hz = ghs_s[dir * 9 + 3 + d], hn = ghs_s[dir * 9 + 6 + d];
      float hp = hv[dir * E_ + h];
      float r = 1.f / (1.f + expf(-(xr + hr)));
      float z = 1.f / (1.f + expf(-(xz + hz)));
      float n = tanhf(xn + r * hn);
      float hnew = (1.f - z) * n + z * hp;
      float resid = dir ? a.dialogue[(size_t)t * E_ + h] : att_s[d];
      float so = hnew + resid;
      astore64(&g_mb_h[((size_t)wg * 8 + sp) * 8 + tid], pk(hnew, tagT));
      astore64(&g_mb_so[(size_t)wg * 8 + tid], pk(so, tagT));
      a.out[(size_t)U_ * E2_ + (size_t)t * E2_ + dir * E_ + h] = so;
    }

    // ============ P3: gather so, global GRU, publish bufgh ============
    {
      const u64* p = &g_mb_so[(size_t)tid * 8];
      u64 x0 = aload64(p),     x1 = aload64(p + 1), x2 = aload64(p + 2);
      u64 x3 = aload64(p + 3), x4 = aload64(p + 4), x5 = aload64(p + 5);
      for (;;) {
        bool ok = (ptag(x0) == tagT) & (ptag(x1) == tagT) & (ptag(x2) == tagT) &
                  (ptag(x3) == tagT) & (ptag(x4) == tagT) & (ptag(x5) == tagT);
        if (ok) break;
        if (ptag(x0) != tagT) x0 = aload64(p);
        if (ptag(x1) != tagT) x1 = aload64(p + 1);
        if (ptag(x2) != tagT) x2 = aload64(p + 2);
        if (ptag(x3) != tagT) x3 = aload64(p + 3);
        if (ptag(x4) != tagT) x4 = aload64(p + 4);
        if (ptag(x5) != tagT) x5 = aload64(p + 5);
      }
      so_f[3 * tid]          = pf(x0);
      so_f[3 * tid + 1]      = pf(x1);
      so_f[3 * tid + 2]      = pf(x2);
      so_f[E_ + 3 * tid]     = pf(x3);
      so_f[E_ + 3 * tid + 1] = pf(x4);
      so_f[E_ + 3 * tid + 2] = pf(x5);
    }
    __syncthreads();
#pragma unroll
    for (int q = 0; q < 5; ++q) {
      int sr = wave + 4 * q;
      if (sr < 18) {
        const float2* so2 = (const float2*)so_f;
        float s = 0.f;
#pragma unroll
        for (int pp = 0; pp < 12; ++pp) {
          int j = lane + 64 * pp;
          u32 v = wGSO[q][pp];
          float2 x = so2[j];
          s = fmaf(bflo(v), x.x, s); s = fmaf(bfhi(v), x.y, s);
        }
        s = wsum(s);
        if (lane == 0) gxs[sr] = s;
      }
    }
    __syncthreads();
    if (tid < 6) {
      int dir = tid / 3, d = tid - dir * 3, h = h0 + d;
      float xr = gxs[dir * 9 + d]     + gxu[dir * 9 + d];
      float xz = gxs[dir * 9 + 3 + d] + gxu[dir * 9 + 3 + d];
      float xn = gxs[dir * 9 + 6 + d] + gxu[dir * 9 + 6 + d];
      float hr = ghg_s[dir * 9 + d], hz = ghg_s[dir * 9 + 3 + d], hn = ghg_s[dir * 9 + 6 + d];
      float hp = ghrow[dir * E_ + h];
      float r = 1.f / (1.f + expf(-(xr + hr)));
      float z = 1.f / (1.f + expf(-(xz + hz)));
      float n = tanhf(xn + r * hn);
      float hnew = (1.f - z) * n + z * hp;
      astore64(&g_mb_bg[(size_t)wg * 8 + tid], pk(hnew, tagT));
      a.out[(size_t)t * E2_ + dir * E_ + h] = hnew;
    }
    __syncthreads();   // protect ghrow/so_f before next step's scatters
  }
}

// ---------------- host ----------------
extern "C" void kernel_launch(void* const* d_in, const int* in_sizes, int n_in,
                              void* d_out, int out_size, void* d_ws, size_t ws_size,
                              hipStream_t stream)
{
  (void)in_sizes; (void)n_in; (void)out_size; (void)d_ws; (void)ws_size;
  const float* dialogue = (const float*)d_in[0];
  const int* speakers = (const int*)d_in[1];
  const float* Wq = (const float*)d_in[2];
  const float* bq = (const float*)d_in[3];
  const float* Wk = (const float*)d_in[4];
  const float* bk = (const float*)d_in[5];
  const float* Wv = (const float*)d_in[6];
  const float* bv = (const float*)d_in[7];
  const float* sWih_f = (const float*)d_in[8];
  const float* sWhh_f = (const float*)d_in[9];
  const float* sbih_f = (const float*)d_in[10];
  const float* sbhh_f = (const float*)d_in[11];
  const float* sWih_b = (const float*)d_in[12];
  const float* sWhh_b = (const float*)d_in[13];
  const float* sbih_b = (const float*)d_in[14];
  const float* sbhh_b = (const float*)d_in[15];
  const float* gWih_f = (const float*)d_in[16];
  const float* gWhh_f = (const float*)d_in[17];
  const float* gbih_f = (const float*)d_in[18];
  const float* gbhh_f = (const float*)d_in[19];
  const float* gWih_b = (const float*)d_in[20];
  const float* gWhh_b = (const float*)d_in[21];
  const float* gbih_b = (const float*)d_in[22];
  const float* gbhh_b = (const float*)d_in[23];
  const float* h0_global = (const float*)d_in[24];
  const float* h0_speaker = (const float*)d_in[25];
  const float* att0 = (const float*)d_in[26];

  init_kernel<<<dim3(12), dim3(256), 0, stream>>>(bk, Wv, bv);

  // g_Q = D @ Wq + bq
  gemm32<0, 0, 0, 0><<<dim3(12, 4), dim3(256), 0, stream>>>(
      dialogue, 768, Wq, 768, bq, 1.f, 768, 256, 768, 768);
  // g_WQg = g_Q @ Wk^T / norm
  gemm32<1, 1, 1, 0><<<dim3(24, 4), dim3(256), 0, stream>>>(
      nullptr, 768, Wk, 768, nullptr, 1.f / NORM_, 1536, 256, 1536, 768);
  // g_WKVT[e][k] = (Wk @ Wv)[k][e]
  gemm32<0, 0, 2, 1><<<dim3(12, 24), dim3(256), 0, stream>>>(
      Wk, 768, Wv, 768, nullptr, 1.f, 1536, 1536, 768, 768);

  SeqArgs args;
  args.dialogue = dialogue;
  args.sWih_f = sWih_f; args.sWih_b = sWih_b; args.sWhh_f = sWhh_f; args.sWhh_b = sWhh_b;
  args.sbih_f = sbih_f; args.sbih_b = sbih_b; args.sbhh_f = sbhh_f; args.sbhh_b = sbhh_b;
  args.gWih_f = gWih_f; args.gWih_b = gWih_b; args.gWhh_f = gWhh_f; args.gWhh_b = gWhh_b;
  args.gbih_f = gbih_f; args.gbih_b = gbih_b; args.gbhh_f = gbhh_f; args.gbhh_b = gbhh_b;
  args.att0 = att0; args.h0g = h0_global; args.h0s = h0_speaker;
  args.speakers = speakers;
  args.out = (float*)d_out;

  seq_kernel<<<dim3(256), dim3(256), 0, stream>>>(args);
}

// Round 3
// 6597.723 us; speedup vs baseline: 2.1620x; 1.0799x over previous
//
#include <hip/hip_runtime.h>
#include <hip/hip_bf16.h>

#define E_ 768
#define E2_ 1536
#define E3_ 2304
#define U_ 256
#define NORM_ 27.712812921102035f
#define NREP 16

typedef unsigned int u32;
typedef unsigned long long u64;

// ---------------- static device workspace ----------------
__device__ __align__(16) float g_Q[U_ * E_];       // D @ Wq + bq
__device__ __align__(16) float g_WQg[U_ * E2_];    // (Wk @ q_t)/norm, row t
__device__ __align__(16) float g_WKVT[E_ * E2_];   // (Wk@Wv)^T : [e][k]
__device__ __align__(16) float g_vb[E_];           // bk@Wv + bv
__device__ int g_run;                              // run counter (tag base)

// mailboxes: u64 = {tag:32 (hi) | fp32 payload (lo)}, replicated NREP x to cut
// same-address poller count from 256 to 16 (LLC line contention was the wall)
__device__ __align__(64) u64 g_mb_bg[NREP * U_ * 8];       // buf row t == gh^t
__device__ __align__(64) u64 g_mb_so[NREP * U_ * 8];       // speaker output
__device__ __align__(64) u64 g_mb_sc[2 * NREP * U_];       // scores (parity by target)
__device__ __align__(64) u64 g_mb_v [NREP * U_ * 4];       // v row dims
__device__ __align__(64) u64 g_mb_h [NREP * U_ * 8 * 8];   // hstate per (block, speaker)

__device__ __forceinline__ float bflo(u32 v){ return __uint_as_float(v << 16); }
__device__ __forceinline__ float bfhi(u32 v){ return __uint_as_float(v & 0xffff0000u); }

__device__ __forceinline__ u32 packbf(float lo, float hi){
  u32 a = __float_as_uint(lo), b = __float_as_uint(hi);
  a = (a + 0x7FFFu + ((a >> 16) & 1u)) >> 16;
  b = (b + 0x7FFFu + ((b >> 16) & 1u)) & 0xFFFF0000u;
  return (a & 0xFFFFu) | b;
}

__device__ __forceinline__ u64 aload64(const u64* p){
  return __hip_atomic_load(p, __ATOMIC_RELAXED, __HIP_MEMORY_SCOPE_AGENT);
}
__device__ __forceinline__ void astore64(u64* p, u64 v){
  __hip_atomic_store(p, v, __ATOMIC_RELAXED, __HIP_MEMORY_SCOPE_AGENT);
}
__device__ __forceinline__ u64 pk(float f, u32 tag){ return (u64)__float_as_uint(f) | ((u64)tag << 32); }
__device__ __forceinline__ float pf(u64 v){ return __uint_as_float((u32)v); }
__device__ __forceinline__ u32 ptag(u64 v){ return (u32)(v >> 32); }

// LDS-only barrier: tag+payload share one atomic u64, so cross-block data needs
// NO store ordering; skipping the vmcnt(0) drain removes store-ack latency from
// every barrier on the critical path.
__device__ __forceinline__ void bar_lds(){
  asm volatile("s_waitcnt lgkmcnt(0)\n\ts_barrier" ::: "memory");
}

__device__ __forceinline__ float wsum(float v){
#pragma unroll
  for (int o = 32; o > 0; o >>= 1) v += __shfl_xor(v, o, 64);
  return v;
}
__device__ __forceinline__ float wmax(float v){
#pragma unroll
  for (int o = 32; o > 0; o >>= 1) v = fmaxf(v, __shfl_xor(v, o, 64));
  return v;
}

// ---------------- init: run counter + vb ----------------
__global__ __launch_bounds__(256) void init_kernel(const float* bk, const float* Wv,
                                                   const float* bv)
{
  __shared__ float acc4[4][64];
  int tid = threadIdx.x;
  if (blockIdx.x == 0 && tid == 0) g_run = g_run + 1;
  int b = blockIdx.x;               // 0..11
  int o = b * 64 + (tid & 63);
  int w = tid >> 6;
  float s = 0.f;
  for (int i2 = w * 192; i2 < w * 192 + 192; ++i2)
    s = fmaf(bk[i2], Wv[(size_t)i2 * E_ + o], s);
  acc4[w][tid & 63] = s;
  __syncthreads();
  if (w == 0)
    g_vb[o] = acc4[0][tid & 63] + acc4[1][tid & 63] + acc4[2][tid & 63] + acc4[3][tid & 63] + bv[o];
}

// ---------------- fp32 tiled GEMM: C = scale*(A@B) + bias ----------------
template<int ASRC, int BNK, int DST, int TC>
__global__ __launch_bounds__(256) void gemm32(const float* __restrict__ Aext, int lda,
                                              const float* __restrict__ B, int ldb,
                                              const float* __restrict__ bias, float scale,
                                              int ldc, int M, int N, int K)
{
  const float* A = (ASRC == 1) ? g_Q : Aext;
  float* C = (DST == 0) ? g_Q : (DST == 1) ? g_WQg : g_WKVT;
  __shared__ float As[64][17];
  __shared__ float Bs[16][65];
  int tid = threadIdx.x;
  int tx = tid & 15, ty = tid >> 4;
  int m0 = blockIdx.y * 64, n0 = blockIdx.x * 64;
  float acc[4][4] = {{0.f}};
  for (int k0 = 0; k0 < K; k0 += 16) {
#pragma unroll
    for (int i = 0; i < 4; ++i) {
      int li = tid + 256 * i;
      int m = li >> 4, kk = li & 15;
      As[m][kk] = A[(size_t)(m0 + m) * lda + k0 + kk];
    }
#pragma unroll
    for (int i = 0; i < 4; ++i) {
      int li = tid + 256 * i;
      if (BNK) {
        int n = li >> 4, kk = li & 15;
        Bs[kk][n] = B[(size_t)(n0 + n) * ldb + k0 + kk];
      } else {
        int kk = li >> 6, n = li & 63;
        Bs[kk][n] = B[(size_t)(k0 + kk) * ldb + n0 + n];
      }
    }
    __syncthreads();
#pragma unroll
    for (int kk = 0; kk < 16; ++kk) {
      float av[4], bv4[4];
#pragma unroll
      for (int i = 0; i < 4; ++i) av[i] = As[ty * 4 + i][kk];
#pragma unroll
      for (int j = 0; j < 4; ++j) bv4[j] = Bs[kk][tx * 4 + j];
#pragma unroll
      for (int i = 0; i < 4; ++i)
#pragma unroll
        for (int j = 0; j < 4; ++j) acc[i][j] = fmaf(av[i], bv4[j], acc[i][j]);
    }
    __syncthreads();
  }
#pragma unroll
  for (int i = 0; i < 4; ++i)
#pragma unroll
    for (int j = 0; j < 4; ++j) {
      int m = m0 + ty * 4 + i, n = n0 + tx * 4 + j;
      float c = acc[i][j] * scale;
      if (bias) c += bias[n];
      if (TC) C[(size_t)n * ldc + m] = c;
      else    C[(size_t)m * ldc + n] = c;
    }
}

// ---------------- persistent sequential kernel ----------------
struct SeqArgs {
  const float *dialogue, *sWih_f, *sWih_b, *sWhh_f, *sWhh_b,
      *sbih_f, *sbih_b, *sbhh_f, *sbhh_b,
      *gWih_f, *gWih_b, *gWhh_f, *gWhh_b, *gbih_f, *gbih_b, *gbhh_f, *gbhh_b,
      *att0, *h0g, *h0s;
  const int* speakers;
  float* out;   // fp32: [U*2E buf][U*2E so]
};

__global__ __launch_bounds__(256, 1) void seq_kernel(SeqArgs a)
{
  const int tid = threadIdx.x, wg = blockIdx.x;
  const int wave = tid >> 6, lane = tid & 63;
  const int h0 = wg * 3;
  const int myrep = wg & (NREP - 1);

  __shared__ float ghs_s[18], ghg_s[18], sxu[18], gxu[18], gxs[18];
  __shared__ float red4[4], red4b[4], att_s[3], pnum[4][4], pmax[4];
  __shared__ float Mvb_l[18], A0_l[18];
  __shared__ float V_lds[U_][3];
  __shared__ float M_l[18][U_];       // M[row][j] = wSA_row . v_j
  __shared__ float ghrow[E2_];        // buf row t-1 == gh^{t-1}
  __shared__ float bufc[E2_];         // this block's own buf row (row wg)
  __shared__ float hv[E2_];           // hstate[sp] fwd/bwd
  __shared__ float so_f[E2_];         // gathered speaker output
  __shared__ float vfull[E_];         // gathered v row t-1
  __shared__ float e_lds[U_];
  __shared__ float pub12[12];         // h[0..5], so[6..11]
  __shared__ float pubbg[6];
  __shared__ int spk_l[U_], locc_l[U_];

  // ---- per-block weight slices: fp32 -> packed bf16 registers ----
  u32 wSA[5][6], wSU[5][6], wSHH[5][6], wGHH[5][6], wGSO[5][12], wGU[5][6];
  float bSH[5], bGH[5], bSI[5], bGI[5];
#pragma unroll
  for (int q = 0; q < 5; ++q) {
    int sr = wave + 4 * q;
    if (sr < 18) {
      int dir = sr / 9, lr = sr - dir * 9, g = lr / 3, d = lr - g * 3;
      int gr = g * E_ + h0 + d;
      const float* pa  = (dir ? a.sWih_b : a.sWih_f) + (size_t)gr * E2_;
      const float* ph  = (dir ? a.sWhh_b : a.sWhh_f) + (size_t)gr * E_;
      const float* pgs = (dir ? a.gWih_b : a.gWih_f) + (size_t)gr * E3_;
      const float* pgh = (dir ? a.gWhh_b : a.gWhh_f) + (size_t)gr * E_;
#pragma unroll
      for (int pp = 0; pp < 6; ++pp) {
        int j2 = 2 * (lane + 64 * pp);
        wSA[q][pp]  = packbf(pa[j2], pa[j2 + 1]);
        wSU[q][pp]  = packbf(pa[768 + j2], pa[768 + j2 + 1]);
        wSHH[q][pp] = packbf(ph[j2], ph[j2 + 1]);
        wGHH[q][pp] = packbf(pgh[j2], pgh[j2 + 1]);
        wGU[q][pp]  = packbf(pgs[1536 + j2], pgs[1536 + j2 + 1]);
      }
#pragma unroll
      for (int pp = 0; pp < 12; ++pp) {
        int j2 = 2 * (lane + 64 * pp);
        wGSO[q][pp] = packbf(pgs[j2], pgs[j2 + 1]);
      }
      bSH[q] = (dir ? a.sbhh_b : a.sbhh_f)[gr];
      bSI[q] = (dir ? a.sbih_b : a.sbih_f)[gr];
      bGH[q] = (dir ? a.gbhh_b : a.gbhh_f)[gr];
      bGI[q] = (dir ? a.gbih_b : a.gbih_f)[gr];
    }
  }
  // ---- wKV: 3 columns of Wk@Wv for this block (fp32) ----
  float wKV[24];
  if (wave < 3) {
    const float* kv = g_WKVT + (size_t)(h0 + wave) * E2_;
#pragma unroll
    for (int pp = 0; pp < 12; ++pp) {
      int j2 = 2 * (lane + 64 * pp);
      wKV[2 * pp] = kv[j2]; wKV[2 * pp + 1] = kv[j2 + 1];
    }
  }
  const float vb0 = g_vb[h0], vb1 = g_vb[h0 + 1], vb2 = g_vb[h0 + 2];

  // ---- speakers + last-occurrence schedule ----
  spk_l[tid] = a.speakers[tid] & 7;
  __syncthreads();
  {
    int mysp = spk_l[tid], lo = -1;
    for (int s2 = tid - 1; s2 >= 0; --s2)
      if (spk_l[s2] == mysp) { lo = s2; break; }
    locc_l[tid] = lo;
  }
  // ---- Mvb = wSA_row . vb ; A0 = wSA_row . att0 ----
#pragma unroll
  for (int q = 0; q < 5; ++q) {
    int sr = wave + 4 * q;
    if (sr < 18) {
      float s0 = 0.f, s1 = 0.f;
#pragma unroll
      for (int pp = 0; pp < 6; ++pp) {
        int j2 = 2 * (lane + 64 * pp);
        u32 w = wSA[q][pp];
        s0 = fmaf(bflo(w), g_vb[j2], s0);  s0 = fmaf(bfhi(w), g_vb[j2 + 1], s0);
        s1 = fmaf(bflo(w), a.att0[j2], s1); s1 = fmaf(bfhi(w), a.att0[j2 + 1], s1);
      }
      s0 = wsum(s0); s1 = wsum(s1);
      if (lane == 0) { Mvb_l[sr] = s0; A0_l[sr] = s1; }
    }
  }
  __syncthreads();

  const u32 rb = ((u32)g_run) << 9;   // unique tag base per run

  for (int t = 0; t < U_; ++t) {
    const int sp = spk_l[t];
    const int locc = locc_l[t];
    const u32 tagT = rb + (u32)t;
    const float2* uv = (const float2*)(a.dialogue + (size_t)t * E_);

    // ---- pre-hop: u-only matvecs (hide producer store flight) ----
#pragma unroll
    for (int q = 0; q < 5; ++q) {
      int sr = wave + 4 * q;
      if (sr < 18) {
        float s3 = 0.f, s4 = 0.f;
#pragma unroll
        for (int pp = 0; pp < 6; ++pp) {
          int j = lane + 64 * pp;
          u32 v3 = wSU[q][pp], v4 = wGU[q][pp];
          float2 xu = uv[j];
          s3 = fmaf(bflo(v3), xu.x, s3); s3 = fmaf(bfhi(v3), xu.y, s3);
          s4 = fmaf(bflo(v4), xu.x, s4); s4 = fmaf(bfhi(v4), xu.y, s4);
        }
        s3 = wsum(s3); s4 = wsum(s4);
        if (lane == 0) { sxu[sr] = s3 + bSI[q]; gxu[sr] = s4 + bGI[q]; }
      }
    }

    // ---- hop A: gather bufgh^{t-1}; local score partial; hv gather ----
    float slp = 0.f;
    if (t == 0) {
      for (int i = tid; i < E2_; i += 256) ghrow[i] = a.h0g[i];
    } else {
      const u64* p = &g_mb_bg[((size_t)myrep * U_ + tid) * 8];
      u64 x0 = aload64(p),     x1 = aload64(p + 1), x2 = aload64(p + 2);
      u64 x3 = aload64(p + 3), x4 = aload64(p + 4), x5 = aload64(p + 5);
      const u32 exp = rb + (u32)(t - 1);
      for (;;) {
        bool ok = (ptag(x0) == exp) & (ptag(x1) == exp) & (ptag(x2) == exp) &
                  (ptag(x3) == exp) & (ptag(x4) == exp) & (ptag(x5) == exp);
        if (ok) break;
        if (ptag(x0) != exp) x0 = aload64(p);
        if (ptag(x1) != exp) x1 = aload64(p + 1);
        if (ptag(x2) != exp) x2 = aload64(p + 2);
        if (ptag(x3) != exp) x3 = aload64(p + 3);
        if (ptag(x4) != exp) x4 = aload64(p + 4);
        if (ptag(x5) != exp) x5 = aload64(p + 5);
      }
      float f0 = pf(x0), f1 = pf(x1), f2 = pf(x2);
      float f3 = pf(x3), f4 = pf(x4), f5 = pf(x5);
      ghrow[3 * tid]          = f0;
      ghrow[3 * tid + 1]      = f1;
      ghrow[3 * tid + 2]      = f2;
      ghrow[E_ + 3 * tid]     = f3;
      ghrow[E_ + 3 * tid + 1] = f4;
      ghrow[E_ + 3 * tid + 2] = f5;
      if (wg == t - 1) {
        bufc[3 * tid]          = f0;
        bufc[3 * tid + 1]      = f1;
        bufc[3 * tid + 2]      = f2;
        bufc[E_ + 3 * tid]     = f3;
        bufc[E_ + 3 * tid + 1] = f4;
        bufc[E_ + 3 * tid + 2] = f5;
      }
      // local score s_{t-1}(t): every block computes it (hop B deleted)
      const float* wq = g_WQg + (size_t)t * E2_;
      slp = f0 * wq[3 * tid] + f1 * wq[3 * tid + 1] + f2 * wq[3 * tid + 2]
          + f3 * wq[E_ + 3 * tid] + f4 * wq[E_ + 3 * tid + 1] + f5 * wq[E_ + 3 * tid + 2];
    }
    if (locc >= 0) {
      const u64* p = &g_mb_h[(((size_t)myrep * U_ + tid) * 8 + sp) * 8];
      u64 x0 = aload64(p),     x1 = aload64(p + 1), x2 = aload64(p + 2);
      u64 x3 = aload64(p + 3), x4 = aload64(p + 4), x5 = aload64(p + 5);
      const u32 exp = rb + (u32)locc;
      for (;;) {
        bool ok = (ptag(x0) == exp) & (ptag(x1) == exp) & (ptag(x2) == exp) &
                  (ptag(x3) == exp) & (ptag(x4) == exp) & (ptag(x5) == exp);
        if (ok) break;
        if (ptag(x0) != exp) x0 = aload64(p);
        if (ptag(x1) != exp) x1 = aload64(p + 1);
        if (ptag(x2) != exp) x2 = aload64(p + 2);
        if (ptag(x3) != exp) x3 = aload64(p + 3);
        if (ptag(x4) != exp) x4 = aload64(p + 4);
        if (ptag(x5) != exp) x5 = aload64(p + 5);
      }
      hv[3 * tid]          = pf(x0);
      hv[3 * tid + 1]      = pf(x1);
      hv[3 * tid + 2]      = pf(x2);
      hv[E_ + 3 * tid]     = pf(x3);
      hv[E_ + 3 * tid + 1] = pf(x4);
      hv[E_ + 3 * tid + 2] = pf(x5);
    } else {
#pragma unroll
      for (int k = 0; k < 6; ++k) {
        int idx = (k / 3) * E_ + 3 * tid + (k % 3);
        hv[idx] = a.h0s[idx];
      }
    }
    slp = wsum(slp);
    if (lane == 0) red4[wave] = slp;
    bar_lds();

    // ---- v own dims: compute + publish ASAP (consumed in P1 by all blocks) ----
    if (t >= 1 && wave < 3) {
      const float2* gr2 = (const float2*)ghrow;
      float s = 0.f;
#pragma unroll
      for (int pp = 0; pp < 12; ++pp) {
        int j = lane + 64 * pp;
        float2 x = gr2[j];
        s = fmaf(wKV[2 * pp], x.x, s);
        s = fmaf(wKV[2 * pp + 1], x.y, s);
      }
      s = wsum(s);
      float vv = s + (wave == 0 ? vb0 : (wave == 1 ? vb1 : vb2));
      if (lane == 0) V_lds[t - 1][wave] = vv;
      if (lane < NREP)
        astore64(&g_mb_v[((size_t)lane * U_ + wg) * 4 + wave], pk(vv, tagT));
    }
    // ---- ahead score for target t+1 (off critical path, 1-hop slack) ----
    if (t >= 1 && wg <= t - 1 && t + 1 < U_) {
      const float2* bc2 = (const float2*)bufc;
      const float2* wq2 = (const float2*)(g_WQg + (size_t)(t + 1) * E2_);
      float sb = 0.f;
#pragma unroll
      for (int pp = 0; pp < 3; ++pp) {
        int j = tid + 256 * pp;
        float2 x = bc2[j];
        float2 w = wq2[j];
        sb = fmaf(x.x, w.x, sb); sb = fmaf(x.y, w.y, sb);
      }
      sb = wsum(sb);
      if (lane == 0) red4b[wave] = sb;
    }
    // ---- recurrent matvecs (hstate, gh) ----
#pragma unroll
    for (int q = 0; q < 5; ++q) {
      int sr = wave + 4 * q;
      if (sr < 18) {
        int dir = sr / 9;
        const float2* hv2 = (const float2*)hv + dir * 384;
        const float2* gv2 = (const float2*)ghrow + dir * 384;
        float s1 = 0.f, s2 = 0.f;
#pragma unroll
        for (int pp = 0; pp < 6; ++pp) {
          int j = lane + 64 * pp;
          u32 v1 = wSHH[q][pp], v2 = wGHH[q][pp];
          float2 xh = hv2[j];
          float2 xg = gv2[j];
          s1 = fmaf(bflo(v1), xh.x, s1); s1 = fmaf(bfhi(v1), xh.y, s1);
          s2 = fmaf(bflo(v2), xg.x, s2); s2 = fmaf(bfhi(v2), xg.y, s2);
        }
        s1 = wsum(s1); s2 = wsum(s2);
        if (lane == 0) { ghs_s[sr] = s1 + bSH[q]; ghg_s[sr] = s2 + bGH[q]; }
      }
    }
    bar_lds();
    if (t >= 1 && wg <= t - 1 && t + 1 < U_ && tid < NREP)
      astore64(&g_mb_sc[(size_t)((t + 1) & 1) * (NREP * U_) + (size_t)tid * U_ + wg],
               pk(red4b[0] + red4b[1] + red4b[2] + red4b[3], rb + (u32)(t + 1)));

    // ============ P1: softmax (all-local scores), M-dot ============
    if (t == 0) {
      if (tid < 18) gxs[tid] = A0_l[tid];
      if (tid < 3) att_s[tid] = a.att0[h0 + tid];
      bar_lds();
    } else {
      float sc;
      if (tid <= t - 2) {
        const u64* p = &g_mb_sc[(size_t)(t & 1) * (NREP * U_) + (size_t)myrep * U_ + tid];
        u64 x = aload64(p);
        while (ptag(x) != tagT) x = aload64(p);
        sc = pf(x);
      } else if (tid == t - 1) {
        sc = red4[0] + red4[1] + red4[2] + red4[3];   // local score
      } else sc = (tid == t) ? 0.f : -3.0e38f;
      float m = wmax(sc);
      if (lane == 0) pmax[wave] = m;
      bar_lds();
      float mall = fmaxf(fmaxf(pmax[0], pmax[1]), fmaxf(pmax[2], pmax[3]));
      float e = 0.f, n0 = 0.f, n1 = 0.f, n2 = 0.f;
      if (tid <= t) {
        e = expf(sc - mall);
        if (tid < t) { n0 = e * V_lds[tid][0]; n1 = e * V_lds[tid][1]; n2 = e * V_lds[tid][2]; }
        else         { n0 = e * vb0; n1 = e * vb1; n2 = e * vb2; }
      }
      e_lds[tid] = e;
      float es = wsum(e); n0 = wsum(n0); n1 = wsum(n1); n2 = wsum(n2);
      if (lane == 0) { pnum[wave][0] = es; pnum[wave][1] = n0; pnum[wave][2] = n1; pnum[wave][3] = n2; }
      // gather v row t-1 (replicated mailbox)
      {
        const u64* p = &g_mb_v[((size_t)myrep * U_ + tid) * 4];
        u64 x0 = aload64(p), x1 = aload64(p + 1), x2 = aload64(p + 2);
        for (;;) {
          bool ok = (ptag(x0) == tagT) & (ptag(x1) == tagT) & (ptag(x2) == tagT);
          if (ok) break;
          if (ptag(x0) != tagT) x0 = aload64(p);
          if (ptag(x1) != tagT) x1 = aload64(p + 1);
          if (ptag(x2) != tagT) x2 = aload64(p + 2);
        }
        vfull[3 * tid]     = pf(x0);
        vfull[3 * tid + 1] = pf(x1);
        vfull[3 * tid + 2] = pf(x2);
      }
      bar_lds();
      float den = pnum[0][0] + pnum[1][0] + pnum[2][0] + pnum[3][0];
      if (tid < 3) {
        float nn = pnum[0][tid + 1] + pnum[1][tid + 1] + pnum[2][tid + 1] + pnum[3][tid + 1];
        att_s[tid] = nn / den;
      }
      const float2* vf2 = (const float2*)vfull;
#pragma unroll
      for (int q = 0; q < 5; ++q) {
        int sr = wave + 4 * q;
        if (sr < 18) {
          float mc = 0.f;
#pragma unroll
          for (int pp = 0; pp < 6; ++pp) {
            int j = lane + 64 * pp;
            u32 v = wSA[q][pp];
            float2 x = vf2[j];
            mc = fmaf(bflo(v), x.x, mc); mc = fmaf(bfhi(v), x.y, mc);
          }
          mc = wsum(mc);
          float dm = 0.f;
#pragma unroll
          for (int pp = 0; pp < 4; ++pp) {
            int j = lane + 64 * pp;
            float ej = e_lds[j];
            float mj = M_l[sr][j];
            dm += (j <= t - 2) ? ej * mj : 0.f;
          }
          dm = wsum(dm);
          if (lane == 0) {
            gxs[sr] = (dm + e_lds[t - 1] * mc + e_lds[t] * Mvb_l[sr]) / den;
            M_l[sr][t - 1] = mc;
          }
        }
      }
      bar_lds();
    }

    // ---- P2: speaker GRU ----
    if (tid < 6) {
      int dir = tid / 3, d = tid - dir * 3, h = h0 + d;
      float xr = gxs[dir * 9 + d]     + sxu[dir * 9 + d];
      float xz = gxs[dir * 9 + 3 + d] + sxu[dir * 9 + 3 + d];
      float xn = gxs[dir * 9 + 6 + d] + sxu[dir * 9 + 6 + d];
      float hr = ghs_s[dir * 9 + d], hz = ghs_s[dir * 9 + 3 + d], hn = ghs_s[dir * 9 + 6 + d];
      float hp = hv[dir * E_ + h];
      float r = 1.f / (1.f + expf(-(xr + hr)));
      float z = 1.f / (1.f + expf(-(xz + hz)));
      float n = tanhf(xn + r * hn);
      float hnew = (1.f - z) * n + z * hp;
      float resid = dir ? a.dialogue[(size_t)t * E_ + h] : att_s[d];
      float so = hnew + resid;
      pub12[tid] = hnew;
      pub12[6 + tid] = so;
      a.out[(size_t)U_ * E2_ + (size_t)t * E2_ + dir * E_ + h] = so;
    }
    bar_lds();
    if (tid < 96) {
      int val = tid >> 4, r2 = tid & (NREP - 1);
      astore64(&g_mb_h[(((size_t)r2 * U_ + wg) * 8 + sp) * 8 + val], pk(pub12[val], tagT));
    } else if (tid < 192) {
      int k = tid - 96, val = k >> 4, r2 = k & (NREP - 1);
      astore64(&g_mb_so[((size_t)r2 * U_ + wg) * 8 + val], pk(pub12[6 + val], tagT));
    }

    // ---- P3: gather so, global GRU, publish bufgh ----
    {
      const u64* p = &g_mb_so[((size_t)myrep * U_ + tid) * 8];
      u64 x0 = aload64(p),     x1 = aload64(p + 1), x2 = aload64(p + 2);
      u64 x3 = aload64(p + 3), x4 = aload64(p + 4), x5 = aload64(p + 5);
      for (;;) {
        bool ok = (ptag(x0) == tagT) & (ptag(x1) == tagT) & (ptag(x2) == tagT) &
                  (ptag(x3) == tagT) & (ptag(x4) == tagT) & (ptag(x5) == tagT);
        if (ok) break;
        if (ptag(x0) != tagT) x0 = aload64(p);
        if (ptag(x1) != tagT) x1 = aload64(p + 1);
        if (ptag(x2) != tagT) x2 = aload64(p + 2);
        if (ptag(x3) != tagT) x3 = aload64(p + 3);
        if (ptag(x4) != tagT) x4 = aload64(p + 4);
        if (ptag(x5) != tagT) x5 = aload64(p + 5);
      }
      so_f[3 * tid]          = pf(x0);
      so_f[3 * tid + 1]      = pf(x1);
      so_f[3 * tid + 2]      = pf(x2);
      so_f[E_ + 3 * tid]     = pf(x3);
      so_f[E_ + 3 * tid + 1] = pf(x4);
      so_f[E_ + 3 * tid + 2] = pf(x5);
    }
    bar_lds();
#pragma unroll
    for (int q = 0; q < 5; ++q) {
      int sr = wave + 4 * q;
      if (sr < 18) {
        const float2* so2 = (const float2*)so_f;
        float s = 0.f;
#pragma unroll
        for (int pp = 0; pp < 12; ++pp) {
          int j = lane + 64 * pp;
          u32 v = wGSO[q][pp];
          float2 x = so2[j];
          s = fmaf(bflo(v), x.x, s); s = fmaf(bfhi(v), x.y, s);
        }
        s = wsum(s);
        if (lane == 0) gxs[sr] = s;
      }
    }
    bar_lds();
    if (tid < 6) {
      int dir = tid / 3, d = tid - dir * 3, h = h0 + d;
      float xr = gxs[dir * 9 + d]     + gxu[dir * 9 + d];
      float xz = gxs[dir * 9 + 3 + d] + gxu[dir * 9 + 3 + d];
      float xn = gxs[dir * 9 + 6 + d] + gxu[dir * 9 + 6 + d];
      float hr = ghg_s[dir * 9 + d], hz = ghg_s[dir * 9 + 3 + d], hn = ghg_s[dir * 9 + 6 + d];
      float hp = ghrow[dir * E_ + h];
      float r = 1.f / (1.f + expf(-(xr + hr)));
      float z = 1.f / (1.f + expf(-(xz + hz)));
      float n = tanhf(xn + r * hn);
      float hnew = (1.f - z) * n + z * hp;
      pubbg[tid] = hnew;
      a.out[(size_t)t * E2_ + dir * E_ + h] = hnew;
    }
    bar_lds();
    if (tid < 96) {
      int val = tid >> 4, r2 = tid & (NREP - 1);
      astore64(&g_mb_bg[((size_t)r2 * U_ + wg) * 8 + val], pk(pubbg[val], tagT));
    }
  }
}

// ---------------- host ----------------
extern "C" void kernel_launch(void* const* d_in, const int* in_sizes, int n_in,
                              void* d_out, int out_size, void* d_ws, size_t ws_size,
                              hipStream_t stream)
{
  (void)in_sizes; (void)n_in; (void)out_size; (void)d_ws; (void)ws_size;
  const float* dialogue = (const float*)d_in[0];
  const int* speakers = (const int*)d_in[1];
  const float* Wq = (const float*)d_in[2];
  const float* bq = (const float*)d_in[3];
  const float* Wk = (const float*)d_in[4];
  const float* bk = (const float*)d_in[5];
  const float* Wv = (const float*)d_in[6];
  const float* bv = (const float*)d_in[7];
  const float* sWih_f = (const float*)d_in[8];
  const float* sWhh_f = (const float*)d_in[9];
  const float* sbih_f = (const float*)d_in[10];
  const float* sbhh_f = (const float*)d_in[11];
  const float* sWih_b = (const float*)d_in[12];
  const float* sWhh_b = (const float*)d_in[13];
  const float* sbih_b = (const float*)d_in[14];
  const float* sbhh_b = (const float*)d_in[15];
  const float* gWih_f = (const float*)d_in[16];
  const float* gWhh_f = (const float*)d_in[17];
  const float* gbih_f = (const float*)d_in[18];
  const float* gbhh_f = (const float*)d_in[19];
  const float* gWih_b = (const float*)d_in[20];
  const float* gWhh_b = (const float*)d_in[21];
  const float* gbih_b = (const float*)d_in[22];
  const float* gbhh_b = (const float*)d_in[23];
  const float* h0_global = (const float*)d_in[24];
  const float* h0_speaker = (const float*)d_in[25];
  const float* att0 = (const float*)d_in[26];

  init_kernel<<<dim3(12), dim3(256), 0, stream>>>(bk, Wv, bv);

  // g_Q = D @ Wq + bq
  gemm32<0, 0, 0, 0><<<dim3(12, 4), dim3(256), 0, stream>>>(
      dialogue, 768, Wq, 768, bq, 1.f, 768, 256, 768, 768);
  // g_WQg = g_Q @ Wk^T / norm
  gemm32<1, 1, 1, 0><<<dim3(24, 4), dim3(256), 0, stream>>>(
      nullptr, 768, Wk, 768, nullptr, 1.f / NORM_, 1536, 256, 1536, 768);
  // g_WKVT[e][k] = (Wk @ Wv)[k][e]
  gemm32<0, 0, 2, 1><<<dim3(12, 24), dim3(256), 0, stream>>>(
      Wk, 768, Wv, 768, nullptr, 1.f, 1536, 1536, 768, 768);

  SeqArgs args;
  args.dialogue = dialogue;
  args.sWih_f = sWih_f; args.sWih_b = sWih_b; args.sWhh_f = sWhh_f; args.sWhh_b = sWhh_b;
  args.sbih_f = sbih_f; args.sbih_b = sbih_b; args.sbhh_f = sbhh_f; args.sbhh_b = sbhh_b;
  args.gWih_f = gWih_f; args.gWih_b = gWih_b; args.gWhh_f = gWhh_f; args.gWhh_b = gWhh_b;
  args.gbih_f = gbih_f; args.gbih_b = gbih_b; args.gbhh_f = gbhh_f; args.gbhh_b = gbhh_b;
  args.att0 = att0; args.h0g = h0_global; args.h0s = h0_speaker;
  args.speakers = speakers;
  args.out = (float*)d_out;

  seq_kernel<<<dim3(256), dim3(256), 0, stream>>>(args);
}